// Round 5
// baseline (126.418 us; speedup 1.0000x reference)
//
#include <hip/hip_runtime.h>
#include <math.h>

#define N_ 8192
#define P_ 512

typedef __fp16 half8  __attribute__((ext_vector_type(8)));
typedef __fp16 half2t __attribute__((ext_vector_type(2)));
typedef float  floatx16 __attribute__((ext_vector_type(16)));

union H8 { half8 v; half2t h2[4]; };

static __device__ __forceinline__ half2t pk2(float a, float b) {
    return __builtin_amdgcn_cvt_pkrtz(a, b);
}

// LDS region0 (bytes):
//   phase A: bpS 512 rows x 48 halfs (96 B/row) = 49152
//   phase C: g1S (32x264 halfs = 16896) @0 ; hpS (32x33 f32 = 4224) @17408 ;
//            xS (32x25 f32 = 3200) @21760 ; wp2S (512 f32 = 2048) @25088
#define HP_OFF  17408
#define XS_OFF  21760
#define WP2_OFF 25088

// 256 blocks x 512 thr. Best-measured base (r4: 108.55us) + three changes:
// 1) GEMM2 batches c=0 AND c=1 (wg2 rows 0..127) prefetched post-p-loop and
//    packed to f16 (32 VGPR); batches 2,3 double-buffered in-loop.
// 2) Wp2 (512 f32 == 1/thread) prefetched to register, staged via LDS during
//    the softmax reduce, read from LDS in phase B.
// 3) Softmax reduce parallelized over 160 threads (5 arrays x 32 cols);
//    1/S folded into phase B as one extra multiply.
// Rationale: __syncthreads drains vmcnt(0), so the post-p-loop prefetch wins
// by ISSUING ALL cold misses concurrently (one ~900cyc round trip) instead
// of stalling serially at each use point. No live range crosses the p-loop.
__global__ __launch_bounds__(512, 4) void k_fused(
    const float* __restrict__ r,
    const float* __restrict__ rp,
    const float* __restrict__ coeff_x,
    const float* __restrict__ coeff_y,
    const float* __restrict__ Wa1,
    const float* __restrict__ Wa2,
    const float* __restrict__ Wa3,
    const float* __restrict__ Wp1,
    const float* __restrict__ bp1,
    const float* __restrict__ Wp2,
    const float* __restrict__ bp2,
    const float* __restrict__ Wg1,
    const float* __restrict__ bg1,
    const float* __restrict__ Wg2,
    const float* __restrict__ bg2,
    const float* __restrict__ Wg3,
    const float* __restrict__ bg3,
    float* __restrict__ out)
{
    __shared__ __align__(16) unsigned char reg0[49152];
    __shared__ __align__(16) float4 cyS[512];
    __shared__ float sA[8][32];          // also reused as redS
    __shared__ float aoA[4][8][32];
    __shared__ float aoS[32][4];
    __shared__ float sredS[32];

    const int tid  = threadIdx.x;
    const int n0   = blockIdx.x * 32;
    const int lane = tid & 63;
    const int wv   = tid >> 6;           // 8 waves
    const int j32  = lane & 31;
    const int hl   = lane >> 5;
    const int k0g  = hl * 8;

    // ================= Phase A: attention =================
    {
        const float2 cx = ((const float2*)coeff_x)[tid];
        half2t* wrow = (half2t*)(reg0 + tid * 96);
#pragma unroll
        for (int q = 0; q < 16; ++q) {
            const float b0 = cx.x * Wa1[64 + 2*q]     + cx.y * Wa1[96 + 2*q];
            const float b1 = cx.x * Wa1[64 + 2*q + 1] + cx.y * Wa1[96 + 2*q + 1];
            wrow[q] = pk2(b0, b1);
        }
        cyS[tid] = ((const float4*)coeff_y)[tid];
    }

    H8 anh1, anh2;
    {
        const float2 rv = ((const float2*)r)[2 * (n0 + j32)];
#pragma unroll
        for (int q = 0; q < 4; ++q) {
            const int k1 = k0g + 2*q, k2 = 16 + k0g + 2*q;
            anh1.h2[q] = pk2(rv.x*Wa1[k1]   + rv.y*Wa1[32+k1],
                             rv.x*Wa1[k1+1] + rv.y*Wa1[32+k1+1]);
            anh2.h2[q] = pk2(rv.x*Wa1[k2]   + rv.y*Wa1[32+k2],
                             rv.x*Wa1[k2+1] + rv.y*Wa1[32+k2+1]);
        }
    }
    H8 af1, af2;
#pragma unroll
    for (int q = 0; q < 4; ++q) {
        af1.h2[q] = pk2(Wa2[(k0g + 2*q)     * 32 + j32],
                        Wa2[(k0g + 2*q + 1) * 32 + j32]);
        af2.h2[q] = pk2(Wa2[(16 + k0g + 2*q)     * 32 + j32],
                        Wa2[(16 + k0g + 2*q + 1) * 32 + j32]);
    }
    half2t w3h[8];
#pragma unroll
    for (int q = 0; q < 8; ++q) {
        const int r0 = ((2*q) & 3) + 8*(q >> 1) + 4*hl;
        w3h[q] = pk2(Wa3[r0], Wa3[r0 + 1]);
    }

    __syncthreads();

    const half2t zero2 = pk2(0.f, 0.f);
    float s = 0.0f, aox = 0.f, aoy = 0.f, aoz = 0.f, aow = 0.f;

#pragma unroll 2
    for (int pl = 0; pl < 64; ++pl) {
        const int ploc = wv * 64 + pl;
        const half2t* rowq = (const half2t*)(reg0 + ploc * 96) + hl * 4;

        H8 bf1, bf2;
#pragma unroll
        for (int q = 0; q < 4; ++q) {
            bf1.h2[q] = __builtin_elementwise_max(anh1.h2[q] + rowq[q],     zero2);
            bf2.h2[q] = __builtin_elementwise_max(anh2.h2[q] + rowq[8 + q], zero2);
        }

        floatx16 zc = {};
        floatx16 acc = __builtin_amdgcn_mfma_f32_32x32x16_f16(af1.v, bf1.v, zc, 0, 0, 0);
        acc = __builtin_amdgcn_mfma_f32_32x32x16_f16(af2.v, bf2.v, acc, 0, 0, 0);

        float d0, d1, d2, d3;
        {
            half2t z0 = __builtin_elementwise_max(pk2(acc[0],  acc[1]),  zero2);
            half2t z1 = __builtin_elementwise_max(pk2(acc[2],  acc[3]),  zero2);
            half2t z2 = __builtin_elementwise_max(pk2(acc[4],  acc[5]),  zero2);
            half2t z3 = __builtin_elementwise_max(pk2(acc[6],  acc[7]),  zero2);
            half2t z4 = __builtin_elementwise_max(pk2(acc[8],  acc[9]),  zero2);
            half2t z5 = __builtin_elementwise_max(pk2(acc[10], acc[11]), zero2);
            half2t z6 = __builtin_elementwise_max(pk2(acc[12], acc[13]), zero2);
            half2t z7 = __builtin_elementwise_max(pk2(acc[14], acc[15]), zero2);
            d0 = __builtin_amdgcn_fdot2(z1, w3h[1], __builtin_amdgcn_fdot2(z0, w3h[0], 0.f, false), false);
            d1 = __builtin_amdgcn_fdot2(z3, w3h[3], __builtin_amdgcn_fdot2(z2, w3h[2], 0.f, false), false);
            d2 = __builtin_amdgcn_fdot2(z5, w3h[5], __builtin_amdgcn_fdot2(z4, w3h[4], 0.f, false), false);
            d3 = __builtin_amdgcn_fdot2(z7, w3h[7], __builtin_amdgcn_fdot2(z6, w3h[6], 0.f, false), false);
        }
        float dot = (d0 + d1) + (d2 + d3);
        dot += __shfl_xor(dot, 32);

        const float e = __expf(dot);   // logits ~N(0,1.3): no-max-sub safe
        const float4 cyv = cyS[ploc];
        s   += e;
        aox += e * cyv.x;
        aoy += e * cyv.y;
        aoz += e * cyv.z;
        aow += e * cyv.w;
    }

    // -------- post-p-loop cold-HBM batched prefetch (phase B/C weights).
    // All loads issue concurrently; the sA barrier drains them in one
    // ~900cyc round trip instead of serial per-use stalls. --------
    const int jcol = (wv << 5) + j32;
    const int nB = tid & 31;
    const int iB = tid >> 5;             // 0..15

    float wg2f[64];                      // GEMM2 batches c=0,1 (rows 0..127)
#pragma unroll
    for (int kk = 0; kk < 8; ++kk)
#pragma unroll
        for (int t = 0; t < 4; ++t) {
            const int kb = kk*16 + hl*8 + 2*t;
            wg2f[kk*8 + 2*t]     = Wg2[kb*256 + jcol];
            wg2f[kk*8 + 2*t + 1] = Wg2[(kb+1)*256 + jcol];
        }
    float wg1f[8], wg1g[8];
    const float bg1v = bg1[jcol];
#pragma unroll
    for (int q = 0; q < 4; ++q) {
        wg1f[2*q]   = Wg1[(k0g + 2*q)*256 + jcol];
        wg1f[2*q+1] = Wg1[(k0g + 2*q + 1)*256 + jcol];
        wg1g[2*q]   = Wg1[(16 + 2*q)*256 + jcol];
        wg1g[2*q+1] = Wg1[(17 + 2*q)*256 + jcol];
    }
    const float wp2pre = Wp2[tid];       // 32x16 = 512 f32, one per thread
    float xpre = 0.f;
    if (tid < 256) {
        const int nn = tid >> 3, k = tid & 7;
        xpre = (k < 4) ? r[(n0+nn)*4 + k] : rp[(n0+nn)*4 + k - 4];
    }
    float wpb[2], wpA[2][4];
#pragma unroll
    for (int rep = 0; rep < 2; ++rep) {
        const int i = iB + rep*16;
        wpb[rep]    = bp1[i];
        wpA[rep][0] = Wp1[i];
        wpA[rep][1] = Wp1[32 + i];
        wpA[rep][2] = Wp1[64 + i];
        wpA[rep][3] = Wp1[96 + i];
    }
    const float bp2v = bp2[iB];
    const float bg2v = bg2[jcol];
    const float w3vv = Wg3[jcol];
    const float bg3v = bg3[0];

    // pack wg2 rows 0..127 to f16 (frees 64 f32 -> 32 VGPR of halves)
    H8 wPre[8];
#pragma unroll
    for (int kk = 0; kk < 8; ++kk)
#pragma unroll
        for (int t = 0; t < 4; ++t)
            wPre[kk].h2[t] = pk2(wg2f[kk*8 + 2*t], wg2f[kk*8 + 2*t + 1]);
    H8 wb1p, wb2p;
#pragma unroll
    for (int q = 0; q < 4; ++q) {
        wb1p.h2[q] = pk2(wg1f[2*q], wg1f[2*q+1]);
        wb2p.h2[q] = (hl == 0) ? pk2(wg1g[2*q], wg1g[2*q+1]) : pk2(0.f, 0.f);
    }

    if (lane < 32) {
        sA[wv][lane]      = s;
        aoA[0][wv][lane]  = aox;
        aoA[1][wv][lane]  = aoy;
        aoA[2][wv][lane]  = aoz;
        aoA[3][wv][lane]  = aow;
    }
    __syncthreads();

    // parallel softmax reduce: 5 arrays x 32 cols = 160 threads; raw sums
    // stored, 1/S applied in phase B. Meanwhile all threads stage Wp2 to LDS.
    float* wp2S = (float*)(reg0 + WP2_OFF);
    wp2S[tid] = wp2pre;
    if (tid < 160) {
        const int g5 = tid >> 5, c = tid & 31;
        if (g5 == 0) {
            float S = 0.f;
#pragma unroll
            for (int w = 0; w < 8; ++w) S += sA[w][c];
            sredS[c] = S;
        } else {
            float A = 0.f;
#pragma unroll
            for (int w = 0; w < 8; ++w) A += aoA[g5-1][w][c];
            aoS[c][g5-1] = A;
        }
    }
    __syncthreads();

    // ================= Phase B: c-MLP + x assembly =================
    float* hpS = (float*)(reg0 + HP_OFF);
    float* xS  = (float*)(reg0 + XS_OFF);

    if (tid < 256) {
        const int nn = tid >> 3, k = tid & 7;
        xS[nn*25 + k] = xpre;
    }
    {
        const float inv = 1.0f / sredS[nB];
        const float a0 = aoS[nB][0], a1 = aoS[nB][1], a2 = aoS[nB][2], a3 = aoS[nB][3];
#pragma unroll
        for (int rep = 0; rep < 2; ++rep) {
            float t = a0*wpA[rep][0] + a1*wpA[rep][1]
                    + a2*wpA[rep][2] + a3*wpA[rep][3];
            float a = wpb[rep] + inv * t;
            hpS[nB*33 + iB + rep*16] = fmaxf(a, 0.0f);
        }
    }
    __syncthreads();

    {
        float a = bp2v;
#pragma unroll
        for (int i = 0; i < 32; ++i) a += hpS[nB*33 + i] * wp2S[i*16 + iB];
        xS[nB*25 + 8 + iB] = a;
    }
    __syncthreads();

    // ================= Phase C: g-network via MFMA =================
    __fp16* g1S = (__fp16*)reg0;

    // GEMM1: g1 = relu(x @ Wg1 + bg1), K=24 padded to 32
    {
        H8 xa1, xa2;
        const float* xrow = xS + j32 * 25;
#pragma unroll
        for (int q = 0; q < 4; ++q) {
            xa1.h2[q] = pk2(xrow[k0g + 2*q], xrow[k0g + 2*q + 1]);
            xa2.h2[q] = (hl == 0) ? pk2(xrow[16 + 2*q], xrow[16 + 2*q + 1])
                                  : pk2(0.f, 0.f);
        }
        floatx16 g1acc = {};
        g1acc = __builtin_amdgcn_mfma_f32_32x32x16_f16(xa1.v, wb1p.v, g1acc, 0, 0, 0);
        g1acc = __builtin_amdgcn_mfma_f32_32x32x16_f16(xa2.v, wb2p.v, g1acc, 0, 0, 0);

#pragma unroll
        for (int i = 0; i < 16; ++i) {
            const int row = (i & 3) + 8*(i >> 2) + 4*hl;
            g1S[row*264 + jcol] = (__fp16)fmaxf(g1acc[i] + bg1v, 0.0f);
        }
    }
    __syncthreads();

    // GEMM2: g2 = relu(g1 @ Wg2 + bg2); dot Wg3; exp.
    // Batches c=0,1 from prefetch (wPre); c=2,3 loaded here, double-buffered
    // under the c=0,1 MFMAs.
    {
        floatx16 acc2 = {};
        const __fp16* arow = g1S + j32 * 264;

        float l2[32];
#pragma unroll
        for (int q = 0; q < 4; ++q)
#pragma unroll
            for (int t = 0; t < 4; ++t) {
                const int kb = (8 + q)*16 + hl*8 + 2*t;
                l2[q*8 + 2*t]     = Wg2[kb*256 + jcol];
                l2[q*8 + 2*t + 1] = Wg2[(kb+1)*256 + jcol];
            }
#pragma unroll
        for (int q = 0; q < 4; ++q) {
            H8 af;
            af.v = *(const half8*)(arow + q*16 + hl*8);
            acc2 = __builtin_amdgcn_mfma_f32_32x32x16_f16(af.v, wPre[q].v, acc2, 0, 0, 0);
        }

        float l3[32];
#pragma unroll
        for (int q = 0; q < 4; ++q)
#pragma unroll
            for (int t = 0; t < 4; ++t) {
                const int kb = (12 + q)*16 + hl*8 + 2*t;
                l3[q*8 + 2*t]     = Wg2[kb*256 + jcol];
                l3[q*8 + 2*t + 1] = Wg2[(kb+1)*256 + jcol];
            }
#pragma unroll
        for (int q = 0; q < 4; ++q) {
            H8 af;
            af.v = *(const half8*)(arow + (4 + q)*16 + hl*8);
            acc2 = __builtin_amdgcn_mfma_f32_32x32x16_f16(af.v, wPre[4+q].v, acc2, 0, 0, 0);
        }

        H8 w2[4];
#pragma unroll
        for (int q = 0; q < 4; ++q)
#pragma unroll
            for (int t = 0; t < 4; ++t)
                w2[q].h2[t] = pk2(l2[q*8 + 2*t], l2[q*8 + 2*t + 1]);
#pragma unroll
        for (int q = 0; q < 4; ++q) {
            H8 af;
            af.v = *(const half8*)(arow + (8 + q)*16 + hl*8);
            acc2 = __builtin_amdgcn_mfma_f32_32x32x16_f16(af.v, w2[q].v, acc2, 0, 0, 0);
        }

        H8 w3[4];
#pragma unroll
        for (int q = 0; q < 4; ++q)
#pragma unroll
            for (int t = 0; t < 4; ++t)
                w3[q].h2[t] = pk2(l3[q*8 + 2*t], l3[q*8 + 2*t + 1]);
#pragma unroll
        for (int q = 0; q < 4; ++q) {
            H8 af;
            af.v = *(const half8*)(arow + (12 + q)*16 + hl*8);
            acc2 = __builtin_amdgcn_mfma_f32_32x32x16_f16(af.v, w3[q].v, acc2, 0, 0, 0);
        }

        float part[16];
#pragma unroll
        for (int i = 0; i < 16; ++i)
            part[i] = fmaxf(acc2[i] + bg2v, 0.0f) * w3vv;
#pragma unroll
        for (int off = 1; off <= 16; off <<= 1) {
#pragma unroll
            for (int i = 0; i < 16; ++i) part[i] += __shfl_xor(part[i], off);
        }
        float* redS = &sA[0][0];
        if ((lane & 31) == 0) {
#pragma unroll
            for (int i = 0; i < 16; ++i) {
                const int row = (i & 3) + 8*(i >> 2) + 4*hl;
                redS[wv*32 + row] = part[i];
            }
        }
        __syncthreads();

        if (tid < 32) {
            float v = bg3v;
#pragma unroll
            for (int w = 0; w < 8; ++w) v += redS[w*32 + tid];
            out[n0 + tid] = __expf(v);
        }
    }
}

extern "C" void kernel_launch(void* const* d_in, const int* in_sizes, int n_in,
                              void* d_out, int out_size, void* d_ws, size_t ws_size,
                              hipStream_t stream)
{
    const float* r   = (const float*)d_in[0];
    const float* rp  = (const float*)d_in[1];
    const float* cx  = (const float*)d_in[2];
    const float* cy  = (const float*)d_in[3];
    const float* Wa1 = (const float*)d_in[4];
    const float* Wa2 = (const float*)d_in[5];
    const float* Wa3 = (const float*)d_in[6];
    const float* Wp1 = (const float*)d_in[7];
    const float* bp1 = (const float*)d_in[8];
    const float* Wp2 = (const float*)d_in[9];
    const float* bp2 = (const float*)d_in[10];
    const float* Wg1 = (const float*)d_in[11];
    const float* bg1 = (const float*)d_in[12];
    const float* Wg2 = (const float*)d_in[13];
    const float* bg2 = (const float*)d_in[14];
    const float* Wg3 = (const float*)d_in[15];
    const float* bg3 = (const float*)d_in[16];

    hipLaunchKernelGGL(k_fused, dim3(N_/32), dim3(512), 0, stream,
                       r, rp, cx, cy, Wa1, Wa2, Wa3, Wp1, bp1, Wp2, bp2,
                       Wg1, bg1, Wg2, bg2, Wg3, bg3, (float*)d_out);
}

// Round 6
// 110.188 us; speedup vs baseline: 1.1473x; 1.1473x over previous
//
#include <hip/hip_runtime.h>
#include <math.h>

#define N_ 8192
#define P_ 512

typedef __fp16 half8  __attribute__((ext_vector_type(8)));
typedef __fp16 half2t __attribute__((ext_vector_type(2)));
typedef float  floatx16 __attribute__((ext_vector_type(16)));

union H8 { half8 v; half2t h2[4]; };

static __device__ __forceinline__ half2t pk2(float a, float b) {
    return __builtin_amdgcn_cvt_pkrtz(a, b);
}

// LDS region0 (bytes):
//   phase A: bpS 512 rows x 48 halfs (96 B/row, 64B used) = 49152
//   phase C: g1S (32x264 halfs = 16896) @0 ; hpS (32x33 f32 = 4224) @17408 ;
//            xS (32x25 f32 = 3200) @21760 ; wp2T (16x33 f32 = 2112) @25088
#define HP_OFF   17408
#define XS_OFF   21760
#define WP2T_OFF 25088

// 256 blocks x 512 thr. r4 base (measured 108.55us) + register-light fixes:
// 1) p-loop: 1-ahead register prefetch of the bpS row (8 VGPR, explicit
//    A/B double-buffer, no loop-carried copies) hides ~120cyc LDS latency.
// 2) parallel softmax reduce (160 thr), 1/S folded into phase B.
// 3) Wp2 staged TRANSPOSED+padded (wp2T[16][33]): phase-B reads are
//    broadcast (uniform per 32-lane group); r5's 16-way conflict removed.
// 4) GEMM2: c=0 from wg2p[32] prefetch (r4 size, NOT r5's 64 -> that
//    spilled: VGPR 64 + 18MB scratch writes); batches c=1..3 hoisted one
//    batch ahead with pack-then-load so only one f32 batch is live.
__global__ __launch_bounds__(512, 4) void k_fused(
    const float* __restrict__ r,
    const float* __restrict__ rp,
    const float* __restrict__ coeff_x,
    const float* __restrict__ coeff_y,
    const float* __restrict__ Wa1,
    const float* __restrict__ Wa2,
    const float* __restrict__ Wa3,
    const float* __restrict__ Wp1,
    const float* __restrict__ bp1,
    const float* __restrict__ Wp2,
    const float* __restrict__ bp2,
    const float* __restrict__ Wg1,
    const float* __restrict__ bg1,
    const float* __restrict__ Wg2,
    const float* __restrict__ bg2,
    const float* __restrict__ Wg3,
    const float* __restrict__ bg3,
    float* __restrict__ out)
{
    __shared__ __align__(16) unsigned char reg0[49152];
    __shared__ __align__(16) float4 cyS[512];
    __shared__ float sA[8][32];          // also reused as redS
    __shared__ float aoA[4][8][32];
    __shared__ float aoS[32][4];
    __shared__ float sredS[32];

    const int tid  = threadIdx.x;
    const int n0   = blockIdx.x * 32;
    const int lane = tid & 63;
    const int wv   = tid >> 6;           // 8 waves
    const int j32  = lane & 31;
    const int hl   = lane >> 5;
    const int k0g  = hl * 8;

    // ================= Phase A: attention =================
    {
        const float2 cx = ((const float2*)coeff_x)[tid];
        half2t* wrow = (half2t*)(reg0 + tid * 96);
#pragma unroll
        for (int q = 0; q < 16; ++q) {
            const float b0 = cx.x * Wa1[64 + 2*q]     + cx.y * Wa1[96 + 2*q];
            const float b1 = cx.x * Wa1[64 + 2*q + 1] + cx.y * Wa1[96 + 2*q + 1];
            wrow[q] = pk2(b0, b1);
        }
        cyS[tid] = ((const float4*)coeff_y)[tid];
    }

    H8 anh1, anh2;
    {
        const float2 rv = ((const float2*)r)[2 * (n0 + j32)];
#pragma unroll
        for (int q = 0; q < 4; ++q) {
            const int k1 = k0g + 2*q, k2 = 16 + k0g + 2*q;
            anh1.h2[q] = pk2(rv.x*Wa1[k1]   + rv.y*Wa1[32+k1],
                             rv.x*Wa1[k1+1] + rv.y*Wa1[32+k1+1]);
            anh2.h2[q] = pk2(rv.x*Wa1[k2]   + rv.y*Wa1[32+k2],
                             rv.x*Wa1[k2+1] + rv.y*Wa1[32+k2+1]);
        }
    }
    H8 af1, af2;
#pragma unroll
    for (int q = 0; q < 4; ++q) {
        af1.h2[q] = pk2(Wa2[(k0g + 2*q)     * 32 + j32],
                        Wa2[(k0g + 2*q + 1) * 32 + j32]);
        af2.h2[q] = pk2(Wa2[(16 + k0g + 2*q)     * 32 + j32],
                        Wa2[(16 + k0g + 2*q + 1) * 32 + j32]);
    }
    half2t w3h[8];
#pragma unroll
    for (int q = 0; q < 8; ++q) {
        const int r0 = ((2*q) & 3) + 8*(q >> 1) + 4*hl;
        w3h[q] = pk2(Wa3[r0], Wa3[r0 + 1]);
    }

    __syncthreads();

    const half2t zero2 = pk2(0.f, 0.f);
    float s = 0.0f, aox = 0.f, aoy = 0.f, aoz = 0.f, aow = 0.f;

    const unsigned char* wbase = reg0 + (wv * 64) * 96 + hl * 16;

    auto ATT = [&](const int ploc, const H8 rq1, const H8 rq2) {
        H8 bf1, bf2;
#pragma unroll
        for (int q = 0; q < 4; ++q) {
            bf1.h2[q] = __builtin_elementwise_max(anh1.h2[q] + rq1.h2[q], zero2);
            bf2.h2[q] = __builtin_elementwise_max(anh2.h2[q] + rq2.h2[q], zero2);
        }
        floatx16 zc = {};
        floatx16 acc = __builtin_amdgcn_mfma_f32_32x32x16_f16(af1.v, bf1.v, zc, 0, 0, 0);
        acc = __builtin_amdgcn_mfma_f32_32x32x16_f16(af2.v, bf2.v, acc, 0, 0, 0);

        float d0, d1, d2, d3;
        {
            half2t z0 = __builtin_elementwise_max(pk2(acc[0],  acc[1]),  zero2);
            half2t z1 = __builtin_elementwise_max(pk2(acc[2],  acc[3]),  zero2);
            half2t z2 = __builtin_elementwise_max(pk2(acc[4],  acc[5]),  zero2);
            half2t z3 = __builtin_elementwise_max(pk2(acc[6],  acc[7]),  zero2);
            half2t z4 = __builtin_elementwise_max(pk2(acc[8],  acc[9]),  zero2);
            half2t z5 = __builtin_elementwise_max(pk2(acc[10], acc[11]), zero2);
            half2t z6 = __builtin_elementwise_max(pk2(acc[12], acc[13]), zero2);
            half2t z7 = __builtin_elementwise_max(pk2(acc[14], acc[15]), zero2);
            d0 = __builtin_amdgcn_fdot2(z1, w3h[1], __builtin_amdgcn_fdot2(z0, w3h[0], 0.f, false), false);
            d1 = __builtin_amdgcn_fdot2(z3, w3h[3], __builtin_amdgcn_fdot2(z2, w3h[2], 0.f, false), false);
            d2 = __builtin_amdgcn_fdot2(z5, w3h[5], __builtin_amdgcn_fdot2(z4, w3h[4], 0.f, false), false);
            d3 = __builtin_amdgcn_fdot2(z7, w3h[7], __builtin_amdgcn_fdot2(z6, w3h[6], 0.f, false), false);
        }
        float dot = (d0 + d1) + (d2 + d3);
        dot += __shfl_xor(dot, 32);

        const float e = __expf(dot);   // logits ~N(0,1.3): no-max-sub safe
        const float4 cyv = cyS[ploc];
        s   += e;
        aox += e * cyv.x;
        aoy += e * cyv.y;
        aoz += e * cyv.z;
        aow += e * cyv.w;
    };

    H8 rA1, rA2, rB1, rB2;
    rA1.v = *(const half8*)(wbase);
    rA2.v = *(const half8*)(wbase + 32);

    for (int pl = 0; pl < 64; pl += 2) {
        const int pb = pl + 1;
        rB1.v = *(const half8*)(wbase + pb*96);
        rB2.v = *(const half8*)(wbase + pb*96 + 32);
        ATT(wv*64 + pl, rA1, rA2);

        const int pn = (pl + 2) & 63;    // wraps at the end; row 0 unused
        rA1.v = *(const half8*)(wbase + pn*96);
        rA2.v = *(const half8*)(wbase + pn*96 + 32);
        ATT(wv*64 + pb, rB1, rB2);
    }

    // -------- post-p-loop cold-HBM batched prefetch (phase B/C weights).
    // All loads issue concurrently; one ~900cyc round trip, drained by the
    // sA barrier, instead of serial per-use stalls. r4-proven sizes. ------
    const int jcol = (wv << 5) + j32;
    const int nB = tid & 31;
    const int iB = tid >> 5;             // 0..15

    float wg2p[32];                      // GEMM2 batch c=0 (rows 0..63)
#pragma unroll
    for (int q = 0; q < 4; ++q)
#pragma unroll
        for (int t = 0; t < 4; ++t) {
            const int kb = q*16 + hl*8 + 2*t;
            wg2p[q*8 + 2*t]     = Wg2[kb*256 + jcol];
            wg2p[q*8 + 2*t + 1] = Wg2[(kb+1)*256 + jcol];
        }
    float wg1f[8], wg1g[8];
    const float bg1v = bg1[jcol];
#pragma unroll
    for (int q = 0; q < 4; ++q) {
        wg1f[2*q]   = Wg1[(k0g + 2*q)*256 + jcol];
        wg1f[2*q+1] = Wg1[(k0g + 2*q + 1)*256 + jcol];
        wg1g[2*q]   = Wg1[(16 + 2*q)*256 + jcol];
        wg1g[2*q+1] = Wg1[(17 + 2*q)*256 + jcol];
    }
    const float wp2pre = Wp2[tid];       // 32x16 = 512 f32, one per thread
    float xpre = 0.f;
    if (tid < 256) {
        const int nn = tid >> 3, k = tid & 7;
        xpre = (k < 4) ? r[(n0+nn)*4 + k] : rp[(n0+nn)*4 + k - 4];
    }
    float wpb[2], wpA[2][4];
#pragma unroll
    for (int rep = 0; rep < 2; ++rep) {
        const int i = iB + rep*16;
        wpb[rep]    = bp1[i];
        wpA[rep][0] = Wp1[i];
        wpA[rep][1] = Wp1[32 + i];
        wpA[rep][2] = Wp1[64 + i];
        wpA[rep][3] = Wp1[96 + i];
    }
    const float bp2v = bp2[iB];
    const float bg2v = bg2[jcol];
    const float w3vv = Wg3[jcol];
    const float bg3v = bg3[0];

    // pack prefetched weights to f16 (frees the f32 regs before the barrier)
    H8 wPre[4];
#pragma unroll
    for (int q = 0; q < 4; ++q)
#pragma unroll
        for (int t = 0; t < 4; ++t)
            wPre[q].h2[t] = pk2(wg2p[q*8 + 2*t], wg2p[q*8 + 2*t + 1]);
    H8 wb1p, wb2p;
#pragma unroll
    for (int q = 0; q < 4; ++q) {
        wb1p.h2[q] = pk2(wg1f[2*q], wg1f[2*q+1]);
        wb2p.h2[q] = (hl == 0) ? pk2(wg1g[2*q], wg1g[2*q+1]) : pk2(0.f, 0.f);
    }

    if (lane < 32) {
        sA[wv][lane]      = s;
        aoA[0][wv][lane]  = aox;
        aoA[1][wv][lane]  = aoy;
        aoA[2][wv][lane]  = aoz;
        aoA[3][wv][lane]  = aow;
    }
    __syncthreads();

    // parallel softmax reduce (160 thr; raw sums, 1/S folded into phase B).
    // All threads stage Wp2 transposed+padded: wp2T[col][row], row-stride 33
    // -> phase-B reads wp2T[iB][i] are BROADCAST (uniform per 32-lane group).
    float* wp2T = (float*)(reg0 + WP2T_OFF);
    wp2T[(tid & 15) * 33 + (tid >> 4)] = wp2pre;
    if (tid < 160) {
        const int g5 = tid >> 5, c = tid & 31;
        if (g5 == 0) {
            float S = 0.f;
#pragma unroll
            for (int w = 0; w < 8; ++w) S += sA[w][c];
            sredS[c] = S;
        } else {
            float A = 0.f;
#pragma unroll
            for (int w = 0; w < 8; ++w) A += aoA[g5-1][w][c];
            aoS[c][g5-1] = A;
        }
    }
    __syncthreads();

    // ================= Phase B: c-MLP + x assembly =================
    float* hpS = (float*)(reg0 + HP_OFF);
    float* xS  = (float*)(reg0 + XS_OFF);

    if (tid < 256) {
        const int nn = tid >> 3, k = tid & 7;
        xS[nn*25 + k] = xpre;
    }
    {
        const float inv = 1.0f / sredS[nB];
        const float a0 = aoS[nB][0], a1 = aoS[nB][1], a2 = aoS[nB][2], a3 = aoS[nB][3];
#pragma unroll
        for (int rep = 0; rep < 2; ++rep) {
            float t = a0*wpA[rep][0] + a1*wpA[rep][1]
                    + a2*wpA[rep][2] + a3*wpA[rep][3];
            float a = wpb[rep] + inv * t;
            hpS[nB*33 + iB + rep*16] = fmaxf(a, 0.0f);
        }
    }
    __syncthreads();

    {
        float a = bp2v;
#pragma unroll
        for (int i = 0; i < 32; ++i) a += hpS[nB*33 + i] * wp2T[iB*33 + i];
        xS[nB*25 + 8 + iB] = a;
    }
    __syncthreads();

    // ================= Phase C: g-network via MFMA =================
    __fp16* g1S = (__fp16*)reg0;

    // GEMM1: g1 = relu(x @ Wg1 + bg1), K=24 padded to 32
    {
        H8 xa1, xa2;
        const float* xrow = xS + j32 * 25;
#pragma unroll
        for (int q = 0; q < 4; ++q) {
            xa1.h2[q] = pk2(xrow[k0g + 2*q], xrow[k0g + 2*q + 1]);
            xa2.h2[q] = (hl == 0) ? pk2(xrow[16 + 2*q], xrow[16 + 2*q + 1])
                                  : pk2(0.f, 0.f);
        }
        floatx16 g1acc = {};
        g1acc = __builtin_amdgcn_mfma_f32_32x32x16_f16(xa1.v, wb1p.v, g1acc, 0, 0, 0);
        g1acc = __builtin_amdgcn_mfma_f32_32x32x16_f16(xa2.v, wb2p.v, g1acc, 0, 0, 0);

#pragma unroll
        for (int i = 0; i < 16; ++i) {
            const int row = (i & 3) + 8*(i >> 2) + 4*hl;
            g1S[row*264 + jcol] = (__fp16)fmaxf(g1acc[i] + bg1v, 0.0f);
        }
    }
    __syncthreads();

    // GEMM2: g2 = relu(g1 @ Wg2 + bg2); dot Wg3; exp.
    // c=0 from wPre; c=1..3 loads hoisted one batch ahead, pack-then-load
    // so at most one f32 batch (32 regs) is live at a time.
    {
        floatx16 acc2 = {};
        const __fp16* arow = g1S + j32 * 264;

        float l1[32];
#pragma unroll
        for (int q = 0; q < 4; ++q)
#pragma unroll
            for (int t = 0; t < 4; ++t) {
                const int kb = (4 + q)*16 + hl*8 + 2*t;
                l1[q*8 + 2*t]     = Wg2[kb*256 + jcol];
                l1[q*8 + 2*t + 1] = Wg2[(kb+1)*256 + jcol];
            }
#pragma unroll
        for (int q = 0; q < 4; ++q) {
            H8 af;
            af.v = *(const half8*)(arow + q*16 + hl*8);
            acc2 = __builtin_amdgcn_mfma_f32_32x32x16_f16(af.v, wPre[q].v, acc2, 0, 0, 0);
        }

        H8 w1[4];
#pragma unroll
        for (int q = 0; q < 4; ++q)
#pragma unroll
            for (int t = 0; t < 4; ++t)
                w1[q].h2[t] = pk2(l1[q*8 + 2*t], l1[q*8 + 2*t + 1]);
        float l2[32];
#pragma unroll
        for (int q = 0; q < 4; ++q)
#pragma unroll
            for (int t = 0; t < 4; ++t) {
                const int kb = (8 + q)*16 + hl*8 + 2*t;
                l2[q*8 + 2*t]     = Wg2[kb*256 + jcol];
                l2[q*8 + 2*t + 1] = Wg2[(kb+1)*256 + jcol];
            }
#pragma unroll
        for (int q = 0; q < 4; ++q) {
            H8 af;
            af.v = *(const half8*)(arow + (4 + q)*16 + hl*8);
            acc2 = __builtin_amdgcn_mfma_f32_32x32x16_f16(af.v, w1[q].v, acc2, 0, 0, 0);
        }

        H8 w2[4];
#pragma unroll
        for (int q = 0; q < 4; ++q)
#pragma unroll
            for (int t = 0; t < 4; ++t)
                w2[q].h2[t] = pk2(l2[q*8 + 2*t], l2[q*8 + 2*t + 1]);
        float l3[32];
#pragma unroll
        for (int q = 0; q < 4; ++q)
#pragma unroll
            for (int t = 0; t < 4; ++t) {
                const int kb = (12 + q)*16 + hl*8 + 2*t;
                l3[q*8 + 2*t]     = Wg2[kb*256 + jcol];
                l3[q*8 + 2*t + 1] = Wg2[(kb+1)*256 + jcol];
            }
#pragma unroll
        for (int q = 0; q < 4; ++q) {
            H8 af;
            af.v = *(const half8*)(arow + (8 + q)*16 + hl*8);
            acc2 = __builtin_amdgcn_mfma_f32_32x32x16_f16(af.v, w2[q].v, acc2, 0, 0, 0);
        }

        H8 w3[4];
#pragma unroll
        for (int q = 0; q < 4; ++q)
#pragma unroll
            for (int t = 0; t < 4; ++t)
                w3[q].h2[t] = pk2(l3[q*8 + 2*t], l3[q*8 + 2*t + 1]);
#pragma unroll
        for (int q = 0; q < 4; ++q) {
            H8 af;
            af.v = *(const half8*)(arow + (12 + q)*16 + hl*8);
            acc2 = __builtin_amdgcn_mfma_f32_32x32x16_f16(af.v, w3[q].v, acc2, 0, 0, 0);
        }

        float part[16];
#pragma unroll
        for (int i = 0; i < 16; ++i)
            part[i] = fmaxf(acc2[i] + bg2v, 0.0f) * w3vv;
#pragma unroll
        for (int off = 1; off <= 16; off <<= 1) {
#pragma unroll
            for (int i = 0; i < 16; ++i) part[i] += __shfl_xor(part[i], off);
        }
        float* redS = &sA[0][0];
        if ((lane & 31) == 0) {
#pragma unroll
            for (int i = 0; i < 16; ++i) {
                const int row = (i & 3) + 8*(i >> 2) + 4*hl;
                redS[wv*32 + row] = part[i];
            }
        }
        __syncthreads();

        if (tid < 32) {
            float v = bg3v;
#pragma unroll
            for (int w = 0; w < 8; ++w) v += redS[w*32 + tid];
            out[n0 + tid] = __expf(v);
        }
    }
}

extern "C" void kernel_launch(void* const* d_in, const int* in_sizes, int n_in,
                              void* d_out, int out_size, void* d_ws, size_t ws_size,
                              hipStream_t stream)
{
    const float* r   = (const float*)d_in[0];
    const float* rp  = (const float*)d_in[1];
    const float* cx  = (const float*)d_in[2];
    const float* cy  = (const float*)d_in[3];
    const float* Wa1 = (const float*)d_in[4];
    const float* Wa2 = (const float*)d_in[5];
    const float* Wa3 = (const float*)d_in[6];
    const float* Wp1 = (const float*)d_in[7];
    const float* bp1 = (const float*)d_in[8];
    const float* Wp2 = (const float*)d_in[9];
    const float* bp2 = (const float*)d_in[10];
    const float* Wg1 = (const float*)d_in[11];
    const float* bg1 = (const float*)d_in[12];
    const float* Wg2 = (const float*)d_in[13];
    const float* bg2 = (const float*)d_in[14];
    const float* Wg3 = (const float*)d_in[15];
    const float* bg3 = (const float*)d_in[16];

    hipLaunchKernelGGL(k_fused, dim3(N_/32), dim3(512), 0, stream,
                       r, rp, cx, cy, Wa1, Wa2, Wa3, Wp1, bp1, Wp2, bp2,
                       Wg1, bg1, Wg2, bg2, Wg3, bg3, (float*)d_out);
}